// Round 2
// baseline (12787.595 us; speedup 1.0000x reference)
//
#include <hip/hip_runtime.h>
#include <cstdint>
#include <cstddef>

#define T_STEPS 2048
#define BATCH   32
#define HID     512
#define NWG_PER_GROUP 32
#define NGROUP  2

typedef __attribute__((ext_vector_type(8))) short          s16x8;
typedef __attribute__((ext_vector_type(4))) float          f32x4;
typedef __attribute__((ext_vector_type(4))) unsigned short u16x4;
typedef unsigned int uint32;

static const size_t XB_BYTES = (size_t)T_STEPS * BATCH * HID * 2;  // 64 MB bf16 x
static const size_t HB_BYTES = (size_t)2 * BATCH * HID * 2;        // h ping-pong

__device__ __forceinline__ unsigned short f2bf(float f) {
    uint32 u = __builtin_bit_cast(uint32, f);
    u += 0x7FFFu + ((u >> 16) & 1u);           // RTNE
    return (unsigned short)(u >> 16);
}
__device__ __forceinline__ float sigm(float x) {
    return __fdividef(1.0f, 1.0f + __expf(-x));
}
__device__ __forceinline__ float tanhfast(float x) {
    float xc = fminf(fmaxf(x, -15.0f), 15.0f);
    float e = __expf(2.0f * xc);
    return __fdividef(e - 1.0f, e + 1.0f);
}

// ---------------- init: h0 -> bf16 ping buffer, zero flags ----------------
__global__ void init_k(const float* __restrict__ h0,
                       unsigned short* __restrict__ hb,
                       uint32* __restrict__ flags) {
    int idx = blockIdx.x * 256 + threadIdx.x;          // 64 blocks -> 16384 threads
    hb[idx]         = f2bf(h0[idx]);                   // buffer 0 = h0
    hb[16384 + idx] = 0;                               // buffer 1 cleared (determinism)
    if (idx < NGROUP * NWG_PER_GROUP * 32) flags[idx] = 0;  // 128B-padded flag words
}

// ---------------- x -> bf16 ----------------
__global__ void xconv_k(const f32x4* __restrict__ x4, u16x4* __restrict__ xb4) {
    int n4 = T_STEPS * BATCH * HID / 4;
    int stride = gridDim.x * 256;
    for (int e = blockIdx.x * 256 + threadIdx.x; e < n4; e += stride) {
        f32x4 v = x4[e];
        u16x4 o;
        o[0] = f2bf(v[0]); o[1] = f2bf(v[1]); o[2] = f2bf(v[2]); o[3] = f2bf(v[3]);
        xb4[e] = o;
    }
}

#define MFMA16 __builtin_amdgcn_mfma_f32_16x16x32_bf16

// ---------------- persistent recurrence ----------------
// grid = 64 WGs: 2 groups (16 batches each) x 32 WGs (16 hidden units each).
// Wave wv (0..3) == gate type (i,f,g,o). Weights [W_hh|W_ih] held in VGPRs.
__launch_bounds__(256, 1)
__global__ void rec_k(const unsigned short* __restrict__ xb,
                      const float* __restrict__ Wih,
                      const float* __restrict__ Whh,
                      const float* __restrict__ bih,
                      const float* __restrict__ bhh,
                      const float* __restrict__ c0,
                      unsigned short* __restrict__ hbuf,   // [2][32][512] bf16
                      uint32* __restrict__ flags,          // [2][32] padded to 128B
                      float* __restrict__ out) {
    const int tid  = threadIdx.x;
    const int lane = tid & 63;
    const int wv   = tid >> 6;            // wave id == gate type
    const int grp  = blockIdx.x >> 5;     // 0..1
    const int w    = blockIdx.x & 31;     // WG within group
    const int b0   = grp * 16;
    const int jr_l = lane & 15;
    const int kh   = lane >> 4;           // 0..3

    __shared__ float gbuf[16 * 64];       // [batch][gate-col] exchange

    // ---- load + convert weight slice into 32 b-fragments (128 VGPRs) ----
    // column c handled by this lane: hidden unit w*16+jr_l, gate type wv
    const int grow = wv * 512 + w * 16 + jr_l;          // row of W_hh / W_ih
    s16x8 bw[32];
    #pragma unroll
    for (int kk = 0; kk < 32; ++kk) {
        const float* s = (kk < 16)
            ? (Whh + (size_t)grow * 512 + kk * 32 + kh * 8)
            : (Wih + (size_t)grow * 512 + (kk - 16) * 32 + kh * 8);
        f32x4 v0 = *(const f32x4*)s;
        f32x4 v1 = *(const f32x4*)(s + 4);
        s16x8 f;
        f[0] = (short)f2bf(v0[0]); f[1] = (short)f2bf(v0[1]);
        f[2] = (short)f2bf(v0[2]); f[3] = (short)f2bf(v0[3]);
        f[4] = (short)f2bf(v1[0]); f[5] = (short)f2bf(v1[1]);
        f[6] = (short)f2bf(v1[2]); f[7] = (short)f2bf(v1[3]);
        bw[kk] = f;
    }

    // ---- cell ownership: 1 cell per thread ----
    const int cb    = tid >> 4;           // batch 0..15 (local)
    const int cj    = tid & 15;           // hidden within slice
    const int j_abs = w * 16 + cj;
    const int gb    = b0 + cb;            // global batch
    float creg  = c0[(size_t)gb * HID + j_abs];
    float bias0 = bih[0 * HID + j_abs] + bhh[0 * HID + j_abs];
    float bias1 = bih[1 * HID + j_abs] + bhh[1 * HID + j_abs];
    float bias2 = bih[2 * HID + j_abs] + bhh[2 * HID + j_abs];
    float bias3 = bih[3 * HID + j_abs] + bhh[3 * HID + j_abs];

    // ---- prefetch x fragments for t=0 ----
    s16x8 xa[16];
    {
        const s16x8* p = (const s16x8*)(xb + ((size_t)0 * BATCH + b0 + jr_l) * HID + kh * 8);
        #pragma unroll
        for (int q = 0; q < 16; ++q) xa[q] = p[q * 4];
    }

    uint32* myflag  = flags + (size_t)(grp * 32 + (lane & 31)) * 32;
    uint32* ourflag = flags + (size_t)(grp * 32 + w) * 32;

    for (int t = 0; t < T_STEPS; ++t) {
        // ---- h fragments from ping-pong buffer (LLC) ----
        const s16x8* hp = (const s16x8*)(hbuf + (size_t)(t & 1) * (BATCH * HID)
                                              + (size_t)(b0 + jr_l) * HID + kh * 8);
        s16x8 ha[16];
        #pragma unroll
        for (int q = 0; q < 16; ++q) ha[q] = hp[q * 4];

        // ---- gates = [h|x] . W^T  (two accumulator chains) ----
        f32x4 accA = {0.f, 0.f, 0.f, 0.f};
        f32x4 accB = {0.f, 0.f, 0.f, 0.f};
        #pragma unroll
        for (int q = 0; q < 8; ++q)  accA = MFMA16(xa[q], bw[16 + q], accA, 0, 0, 0);
        #pragma unroll
        for (int q = 8; q < 16; ++q) accB = MFMA16(xa[q], bw[16 + q], accB, 0, 0, 0);
        #pragma unroll
        for (int q = 0; q < 8; ++q)  accA = MFMA16(ha[q], bw[q], accA, 0, 0, 0);
        #pragma unroll
        for (int q = 8; q < 16; ++q) accB = MFMA16(ha[q], bw[q], accB, 0, 0, 0);
        f32x4 acc = accA + accB;

        // D frag: row(batch) = kh*4+q, col = wv*16 + jr_l
        #pragma unroll
        for (int q = 0; q < 4; ++q)
            gbuf[(kh * 4 + q) * 64 + wv * 16 + jr_l] = acc[q];
        __syncthreads();

        // ---- cell update ----
        float pi = gbuf[cb * 64 +  0 + cj] + bias0;
        float pf = gbuf[cb * 64 + 16 + cj] + bias1;
        float pg = gbuf[cb * 64 + 32 + cj] + bias2;
        float po = gbuf[cb * 64 + 48 + cj] + bias3;
        float ig = sigm(pi), fg = sigm(pf), gg = tanhfast(pg), og = sigm(po);
        creg = fg * creg + ig * gg;
        float hv = og * tanhfast(creg);

        out[((size_t)t * BATCH + gb) * HID + j_abs] = hv;
        hbuf[(size_t)((t + 1) & 1) * (BATCH * HID) + (size_t)gb * HID + j_abs] = f2bf(hv);
        if (t == T_STEPS - 1) {
            out[(size_t)T_STEPS * BATCH * HID + (size_t)gb * HID + j_abs] = hv;       // h_T
            out[(size_t)T_STEPS * BATCH * HID + BATCH * HID
                + (size_t)gb * HID + j_abs] = creg;                                    // c_T
        }
        __syncthreads();   // compiler drains vmcnt before s_barrier -> all WG stores in L2

        // release: flush this WG's h stores to LLC, then publish flag
        if (tid == 0)
            __hip_atomic_store(ourflag, (uint32)(t + 1),
                               __ATOMIC_RELEASE, __HIP_MEMORY_SCOPE_AGENT);

        // ---- prefetch next x while waiting ----
        {
            int tn = (t + 1 < T_STEPS) ? (t + 1) : t;
            const s16x8* p = (const s16x8*)(xb + ((size_t)tn * BATCH + b0 + jr_l) * HID + kh * 8);
            #pragma unroll
            for (int q = 0; q < 16; ++q) xa[q] = p[q * 4];
        }

        // ---- wait for all 32 producers of this group (lane-parallel poll) ----
        if (t + 1 < T_STEPS) {
            uint32 target = (uint32)(t + 1);
            while (true) {
                uint32 v = __hip_atomic_load(myflag, __ATOMIC_RELAXED, __HIP_MEMORY_SCOPE_AGENT);
                int ok = (lane < 32) ? (v >= target) : 1;
                if (__all(ok)) break;
                __builtin_amdgcn_s_sleep(1);
            }
            __builtin_amdgcn_fence(__ATOMIC_ACQUIRE, "agent");  // invalidate L1/L2 for fresh h
        }
    }
}

extern "C" void kernel_launch(void* const* d_in, const int* in_sizes, int n_in,
                              void* d_out, int out_size, void* d_ws, size_t ws_size,
                              hipStream_t stream) {
    const float* x   = (const float*)d_in[0];
    const float* h0  = (const float*)d_in[1];
    const float* c0  = (const float*)d_in[2];
    const float* Wih = (const float*)d_in[3];
    const float* Whh = (const float*)d_in[4];
    const float* bih = (const float*)d_in[5];
    const float* bhh = (const float*)d_in[6];
    float* out = (float*)d_out;

    char* ws = (char*)d_ws;
    unsigned short* xb    = (unsigned short*)ws;
    unsigned short* hbuf  = (unsigned short*)(ws + XB_BYTES);
    uint32*         flags = (uint32*)(ws + XB_BYTES + HB_BYTES);

    init_k<<<dim3(64), dim3(256), 0, stream>>>(h0, hbuf, flags);
    xconv_k<<<dim3(4096), dim3(256), 0, stream>>>((const f32x4*)x, (u16x4*)xb);
    rec_k<<<dim3(NGROUP * NWG_PER_GROUP), dim3(256), 0, stream>>>(
        xb, Wih, Whh, bih, bhh, c0, hbuf, flags, out);
}

// Round 3
// 10635.277 us; speedup vs baseline: 1.2024x; 1.2024x over previous
//
#include <hip/hip_runtime.h>
#include <cstdint>
#include <cstddef>

#define T_STEPS 2048
#define BATCH   32
#define HID     512
#define NWG_PER_GROUP 32
#define NGROUP  2

typedef __attribute__((ext_vector_type(8))) short          s16x8;
typedef __attribute__((ext_vector_type(4))) float          f32x4;
typedef __attribute__((ext_vector_type(4))) unsigned short u16x4;
typedef unsigned int uint32;

static const size_t XB_BYTES = (size_t)T_STEPS * BATCH * HID * 2;  // 64 MB bf16 x
static const size_t HB_BYTES = (size_t)2 * BATCH * HID * 2;        // h ping-pong

__device__ __forceinline__ unsigned short f2bf(float f) {
    uint32 u = __builtin_bit_cast(uint32, f);
    u += 0x7FFFu + ((u >> 16) & 1u);           // RTNE
    return (unsigned short)(u >> 16);
}
__device__ __forceinline__ float sigm(float x) {
    return __fdividef(1.0f, 1.0f + __expf(-x));
}
__device__ __forceinline__ float tanhfast(float x) {
    float xc = fminf(fmaxf(x, -15.0f), 15.0f);
    float e = __expf(2.0f * xc);
    return __fdividef(e - 1.0f, e + 1.0f);
}

// LLC-coherent (cross-XCD) 16B load: bypasses stale L1/L2 copies.
__device__ __forceinline__ s16x8 llc_load16(const unsigned short* p) {
    s16x8 r;
    asm volatile("global_load_dwordx4 %0, %1, off sc0 sc1"
                 : "=v"(r) : "v"(p) : "memory");
    return r;   // NOT ready until an explicit s_waitcnt vmcnt!
}
// LLC-coherent 2B store: write-through to coherence point (no dirty L2 line).
__device__ __forceinline__ void llc_store2(unsigned short* p, uint32 v) {
    asm volatile("global_store_short %0, %1, off sc0 sc1"
                 :: "v"(p), "v"(v) : "memory");
}

// ---------------- init: h0 -> bf16 ping buffer, zero flags ----------------
__global__ void init_k(const float* __restrict__ h0,
                       unsigned short* __restrict__ hb,
                       uint32* __restrict__ flags) {
    int idx = blockIdx.x * 256 + threadIdx.x;          // 64 blocks -> 16384 threads
    hb[idx]         = f2bf(h0[idx]);                   // buffer 0 = h0
    hb[16384 + idx] = 0;                               // buffer 1 cleared (determinism)
    if (idx < NGROUP * NWG_PER_GROUP * 32) flags[idx] = 0;  // 128B-padded flag words
}

// ---------------- x -> bf16 ----------------
__global__ void xconv_k(const f32x4* __restrict__ x4, u16x4* __restrict__ xb4) {
    int n4 = T_STEPS * BATCH * HID / 4;
    int stride = gridDim.x * 256;
    for (int e = blockIdx.x * 256 + threadIdx.x; e < n4; e += stride) {
        f32x4 v = x4[e];
        u16x4 o;
        o[0] = f2bf(v[0]); o[1] = f2bf(v[1]); o[2] = f2bf(v[2]); o[3] = f2bf(v[3]);
        xb4[e] = o;
    }
}

#define MFMA16 __builtin_amdgcn_mfma_f32_16x16x32_bf16

// ---------------- persistent recurrence ----------------
// grid = 64 WGs: 2 groups (16 batches each) x 32 WGs (16 hidden units each).
// Wave wv (0..3) == gate type (i,f,g,o). Weights [W_hh|W_ih] held in VGPRs.
// Cross-WG h exchange via write-through sc0sc1 stores + relaxed agent flags;
// NO acquire/release fences in the loop (no buffer_inv / buffer_wbl2).
__launch_bounds__(256, 1)
__global__ void rec_k(const unsigned short* __restrict__ xb,
                      const float* __restrict__ Wih,
                      const float* __restrict__ Whh,
                      const float* __restrict__ bih,
                      const float* __restrict__ bhh,
                      const float* __restrict__ c0,
                      unsigned short* __restrict__ hbuf,   // [2][32][512] bf16
                      uint32* __restrict__ flags,          // [2*32] padded to 128B
                      float* __restrict__ out) {
    const int tid  = threadIdx.x;
    const int lane = tid & 63;
    const int wv   = tid >> 6;            // wave id == gate type
    const int grp  = blockIdx.x >> 5;     // 0..1
    const int w    = blockIdx.x & 31;     // WG within group
    const int b0   = grp * 16;
    const int jr_l = lane & 15;
    const int kh   = lane >> 4;           // 0..3

    __shared__ float gbuf[16 * 64];       // [batch][gate-col] exchange

    // ---- load + convert weight slice into 32 b-fragments (128 VGPRs) ----
    const int grow = wv * 512 + w * 16 + jr_l;          // row of W_hh / W_ih
    s16x8 bw[32];
    #pragma unroll
    for (int kk = 0; kk < 32; ++kk) {
        const float* s = (kk < 16)
            ? (Whh + (size_t)grow * 512 + kk * 32 + kh * 8)
            : (Wih + (size_t)grow * 512 + (kk - 16) * 32 + kh * 8);
        f32x4 v0 = *(const f32x4*)s;
        f32x4 v1 = *(const f32x4*)(s + 4);
        s16x8 f;
        f[0] = (short)f2bf(v0[0]); f[1] = (short)f2bf(v0[1]);
        f[2] = (short)f2bf(v0[2]); f[3] = (short)f2bf(v0[3]);
        f[4] = (short)f2bf(v1[0]); f[5] = (short)f2bf(v1[1]);
        f[6] = (short)f2bf(v1[2]); f[7] = (short)f2bf(v1[3]);
        bw[kk] = f;
    }

    // ---- cell ownership: 1 cell per thread ----
    const int cb    = tid >> 4;           // batch 0..15 (local)
    const int cj    = tid & 15;           // hidden within slice
    const int j_abs = w * 16 + cj;
    const int gb    = b0 + cb;            // global batch
    float creg  = c0[(size_t)gb * HID + j_abs];
    float bias0 = bih[0 * HID + j_abs] + bhh[0 * HID + j_abs];
    float bias1 = bih[1 * HID + j_abs] + bhh[1 * HID + j_abs];
    float bias2 = bih[2 * HID + j_abs] + bhh[2 * HID + j_abs];
    float bias3 = bih[3 * HID + j_abs] + bhh[3 * HID + j_abs];

    // ---- prefetch x fragments for t=0 (normal cached loads) ----
    s16x8 xa[16];
    {
        const s16x8* p = (const s16x8*)(xb + ((size_t)0 * BATCH + b0 + jr_l) * HID + kh * 8);
        #pragma unroll
        for (int q = 0; q < 16; ++q) xa[q] = p[q * 4];
    }

    uint32* myflag  = flags + (size_t)(grp * 32 + (lane & 31)) * 32;
    uint32* ourflag = flags + (size_t)(grp * 32 + w) * 32;

    for (int t = 0; t < T_STEPS; ++t) {
        // ---- issue h fragment loads (coherent, from LLC) ----
        const unsigned short* hpb = hbuf + (size_t)(t & 1) * (BATCH * HID)
                                         + (size_t)(b0 + jr_l) * HID + kh * 8;
        s16x8 ha[16];
        #pragma unroll
        for (int q = 0; q < 16; ++q) ha[q] = llc_load16(hpb + q * 32);

        // ---- x-part MFMAs (xa prefetched last iter; overlaps h-load latency) ----
        f32x4 accA = {0.f, 0.f, 0.f, 0.f};
        f32x4 accB = {0.f, 0.f, 0.f, 0.f};
        #pragma unroll
        for (int q = 0; q < 8; ++q)  accA = MFMA16(xa[q], bw[16 + q], accA, 0, 0, 0);
        #pragma unroll
        for (int q = 8; q < 16; ++q) accB = MFMA16(xa[q], bw[16 + q], accB, 0, 0, 0);

        // h asm loads must land before use (rule 18: waitcnt + sched_barrier)
        asm volatile("s_waitcnt vmcnt(0)" ::: "memory");
        __builtin_amdgcn_sched_barrier(0);

        #pragma unroll
        for (int q = 0; q < 8; ++q)  accA = MFMA16(ha[q], bw[q], accA, 0, 0, 0);
        #pragma unroll
        for (int q = 8; q < 16; ++q) accB = MFMA16(ha[q], bw[q], accB, 0, 0, 0);
        f32x4 acc = accA + accB;

        // D frag: row(batch) = kh*4+q, col = wv*16 + jr_l
        #pragma unroll
        for (int q = 0; q < 4; ++q)
            gbuf[(kh * 4 + q) * 64 + wv * 16 + jr_l] = acc[q];
        __syncthreads();

        // ---- cell update ----
        float pi = gbuf[cb * 64 +  0 + cj] + bias0;
        float pf = gbuf[cb * 64 + 16 + cj] + bias1;
        float pg = gbuf[cb * 64 + 32 + cj] + bias2;
        float po = gbuf[cb * 64 + 48 + cj] + bias3;
        float ig = sigm(pi), fg = sigm(pf), gg = tanhfast(pg), og = sigm(po);
        creg = fg * creg + ig * gg;
        float hv = og * tanhfast(creg);

        // h for next step: write-through to LLC
        llc_store2(hbuf + (size_t)((t + 1) & 1) * (BATCH * HID)
                        + (size_t)gb * HID + j_abs, (uint32)f2bf(hv));
        out[((size_t)t * BATCH + gb) * HID + j_abs] = hv;
        if (t == T_STEPS - 1) {
            out[(size_t)T_STEPS * BATCH * HID + (size_t)gb * HID + j_abs] = hv;       // h_T
            out[(size_t)T_STEPS * BATCH * HID + BATCH * HID
                + (size_t)gb * HID + j_abs] = creg;                                    // c_T
        }

        // manual release: drain this wave's stores, then barrier covers all 4 waves
        asm volatile("s_waitcnt vmcnt(0)" ::: "memory");
        __syncthreads();
        if (tid == 0)
            __hip_atomic_store(ourflag, (uint32)(t + 1),
                               __ATOMIC_RELAXED, __HIP_MEMORY_SCOPE_AGENT);

        // ---- prefetch next x while waiting (normal cached loads) ----
        {
            int tn = (t + 1 < T_STEPS) ? (t + 1) : t;
            const s16x8* p = (const s16x8*)(xb + ((size_t)tn * BATCH + b0 + jr_l) * HID + kh * 8);
            #pragma unroll
            for (int q = 0; q < 16; ++q) xa[q] = p[q * 4];
        }

        // ---- wait for all 32 producers of this group (lane-parallel poll) ----
        if (t + 1 < T_STEPS) {
            uint32 target = (uint32)(t + 1);
            while (true) {
                uint32 v = __hip_atomic_load(myflag, __ATOMIC_RELAXED, __HIP_MEMORY_SCOPE_AGENT);
                int ok = (lane < 32) ? (v >= target) : 1;
                if (__all(ok)) break;
            }
            // no acquire fence: h body is read with sc0sc1 (coherent) loads
        }
    }
}

extern "C" void kernel_launch(void* const* d_in, const int* in_sizes, int n_in,
                              void* d_out, int out_size, void* d_ws, size_t ws_size,
                              hipStream_t stream) {
    const float* x   = (const float*)d_in[0];
    const float* h0  = (const float*)d_in[1];
    const float* c0  = (const float*)d_in[2];
    const float* Wih = (const float*)d_in[3];
    const float* Whh = (const float*)d_in[4];
    const float* bih = (const float*)d_in[5];
    const float* bhh = (const float*)d_in[6];
    float* out = (float*)d_out;

    char* ws = (char*)d_ws;
    unsigned short* xb    = (unsigned short*)ws;
    unsigned short* hbuf  = (unsigned short*)(ws + XB_BYTES);
    uint32*         flags = (uint32*)(ws + XB_BYTES + HB_BYTES);

    init_k<<<dim3(64), dim3(256), 0, stream>>>(h0, hbuf, flags);
    xconv_k<<<dim3(4096), dim3(256), 0, stream>>>((const f32x4*)x, (u16x4*)xb);
    rec_k<<<dim3(NGROUP * NWG_PER_GROUP), dim3(256), 0, stream>>>(
        xb, Wih, Whh, bih, bhh, c0, hbuf, flags, out);
}

// Round 4
// 9388.311 us; speedup vs baseline: 1.3621x; 1.1328x over previous
//
#include <hip/hip_runtime.h>
#include <cstdint>
#include <cstddef>

#define T_STEPS 2048
#define BATCH   32
#define HID     512
#define NG      2048            // 4*HID gate rows

typedef __attribute__((ext_vector_type(8))) short        s16x8;
typedef __attribute__((ext_vector_type(4))) float        f32x4;
typedef __attribute__((ext_vector_type(4))) unsigned int u32x4;
typedef unsigned int u32;

static const size_t XP_BYTES = (size_t)T_STEPS * NG * BATCH * 2;   // 256 MB bf16
#define SLOT_ELEMS (BATCH * HID)                                   // 16384

__device__ __forceinline__ unsigned short f2bf(float f) {
    u32 u = __builtin_bit_cast(u32, f);
    u += 0x7FFFu + ((u >> 16) & 1u);           // RTNE
    return (unsigned short)(u >> 16);
}
__device__ __forceinline__ float bf2f(u32 h) {      // h: bf16 in low 16 bits
    return __builtin_bit_cast(float, h << 16);
}
__device__ __forceinline__ float sigm(float x) {
    return __fdividef(1.0f, 1.0f + __expf(-x));
}
__device__ __forceinline__ float tanhfast(float x) {
    float xc = fminf(fmaxf(x, -15.0f), 15.0f);
    float e = __expf(2.0f * xc);
    return __fdividef(e - 1.0f, e + 1.0f);
}
// LLC-coherent (cross-XCD) 16B load; NOT ready until explicit s_waitcnt vmcnt.
__device__ __forceinline__ s16x8 llc_load16(const unsigned short* p) {
    s16x8 r;
    asm volatile("global_load_dwordx4 %0, %1, off sc0 sc1"
                 : "=v"(r) : "v"(p) : "memory");
    return r;
}
// LLC-coherent 4B store (fire-and-forget write-through).
__device__ __forceinline__ void llc_store4(unsigned short* p, u32 v) {
    asm volatile("global_store_dword %0, %1, off sc0 sc1"
                 :: "v"(p), "v"(v) : "memory");
}

#define MFMA16 __builtin_amdgcn_mfma_f32_16x16x32_bf16

// ---------------- init: slot0 = h0 (bf16), slots 1,2 = sentinel ----------------
__global__ void init_k(const float* __restrict__ h0, unsigned short* __restrict__ hb) {
    int idx = blockIdx.x * 256 + threadIdx.x;          // grid 192 -> 49152 threads
    if (idx < SLOT_ELEMS) hb[idx] = f2bf(h0[idx]);
    else                  hb[idx] = 0xFFFFu;           // sentinel
}

// ---------------- xproj: xp[t][g][b] = (x @ Wih^T)[t][b][g] + bih[g] + bhh[g] ----
// grid = 256 WGs x 256 thr: 32 gate-blocks (64 gates) x 8 t-chunks (256 t each).
__launch_bounds__(256, 1)
__global__ void xproj_k(const float* __restrict__ x, const float* __restrict__ Wih,
                        const float* __restrict__ bih, const float* __restrict__ bhh,
                        unsigned short* __restrict__ xp) {
    const int tid = threadIdx.x, lane = tid & 63, wv = tid >> 6;
    const int gblk = blockIdx.x & 31, tch = blockIdx.x >> 5;
    const int g0 = gblk * 64 + wv * 16;       // wave's 16 gate rows
    const int jr = lane & 15, kq = lane >> 4;

    __shared__ unsigned short xs[32][520];    // x[t] as bf16, +8 pad

    // A-frags: Wih[g0+jr][k], K=512 -> 16 frags
    s16x8 aw[16];
    #pragma unroll
    for (int kf = 0; kf < 16; ++kf) {
        const float* s = Wih + (size_t)(g0 + jr) * 512 + kf * 32 + kq * 8;
        f32x4 v0 = *(const f32x4*)s, v1 = *(const f32x4*)(s + 4);
        s16x8 f;
        f[0]=(short)f2bf(v0[0]); f[1]=(short)f2bf(v0[1]); f[2]=(short)f2bf(v0[2]); f[3]=(short)f2bf(v0[3]);
        f[4]=(short)f2bf(v1[0]); f[5]=(short)f2bf(v1[1]); f[6]=(short)f2bf(v1[2]); f[7]=(short)f2bf(v1[3]);
        aw[kf] = f;
    }
    float bias[4];
    #pragma unroll
    for (int q = 0; q < 4; ++q) bias[q] = bih[g0 + kq*4 + q] + bhh[g0 + kq*4 + q];

    const int lb = tid & 31;          // coop-load batch
    const int lk = (tid >> 5) * 64;   // coop-load k base

    for (int t = tch * 256; t < tch * 256 + 256; ++t) {
        // cooperative x[t] -> LDS bf16
        const float* src = x + ((size_t)t * BATCH + lb) * 512 + lk;
        #pragma unroll
        for (int i = 0; i < 8; ++i) {
            f32x4 a = *(const f32x4*)(src + i * 8);
            f32x4 b = *(const f32x4*)(src + i * 8 + 4);
            s16x8 f;
            f[0]=(short)f2bf(a[0]); f[1]=(short)f2bf(a[1]); f[2]=(short)f2bf(a[2]); f[3]=(short)f2bf(a[3]);
            f[4]=(short)f2bf(b[0]); f[5]=(short)f2bf(b[1]); f[6]=(short)f2bf(b[2]); f[7]=(short)f2bf(b[3]);
            *(s16x8*)&xs[lb][lk + i * 8] = f;
        }
        __syncthreads();
        f32x4 acc0 = {0,0,0,0}, acc1 = {0,0,0,0};
        #pragma unroll
        for (int kf = 0; kf < 16; ++kf) {
            s16x8 xb0 = *(const s16x8*)&xs[jr][kf * 32 + kq * 8];
            s16x8 xb1 = *(const s16x8*)&xs[16 + jr][kf * 32 + kq * 8];
            acc0 = MFMA16(aw[kf], xb0, acc0, 0, 0, 0);
            acc1 = MFMA16(aw[kf], xb1, acc1, 0, 0, 0);
        }
        __syncthreads();
        #pragma unroll
        for (int q = 0; q < 4; ++q) {
            int g = g0 + kq * 4 + q;                     // D row = gate
            xp[((size_t)t * NG + g) * 32 + jr]      = f2bf(acc0[q] + bias[q]);
            xp[((size_t)t * NG + g) * 32 + 16 + jr] = f2bf(acc1[q] + bias[q]);
        }
    }
}

// ---------------- persistent recurrence: 64 WGs x 64 threads (1 wave) ----------
// Wave = (group grp: 16 batches) x (hid block w: 16 hid x 4 gates).
// Depth-3 rotating h buffer, dword sentinels, no flags, no barriers.
__launch_bounds__(64, 1)
__global__ void rec_k(const unsigned short* __restrict__ xp,
                      const float* __restrict__ Whh,
                      const float* __restrict__ c0,
                      unsigned short* __restrict__ hbuf,   // [3][32][512] bf16
                      float* __restrict__ out) {
    const int lane = threadIdx.x & 63;
    const int grp  = blockIdx.x >> 5;     // 0..1
    const int w    = blockIdx.x & 31;     // hid block
    const int b0   = grp * 16;
    const int jr   = lane & 15, kq = lane >> 4;
    const int j16  = w * 16 + jr;

    // B-frags: Whh[cf*512 + j16][k] for 4 gates x 16 k-frags (256 VGPR)
    s16x8 bw[4][16];
    #pragma unroll
    for (int cf = 0; cf < 4; ++cf) {
        #pragma unroll
        for (int kf = 0; kf < 16; ++kf) {
            const float* s = Whh + (size_t)(cf * 512 + j16) * 512 + kf * 32 + kq * 8;
            f32x4 v0 = *(const f32x4*)s, v1 = *(const f32x4*)(s + 4);
            s16x8 f;
            f[0]=(short)f2bf(v0[0]); f[1]=(short)f2bf(v0[1]); f[2]=(short)f2bf(v0[2]); f[3]=(short)f2bf(v0[3]);
            f[4]=(short)f2bf(v1[0]); f[5]=(short)f2bf(v1[1]); f[6]=(short)f2bf(v1[2]); f[7]=(short)f2bf(v1[3]);
            bw[cf][kf] = f;
        }
    }

    // cell state: 4 batches (rows kq*4+q), hid j16
    float creg[4];
    #pragma unroll
    for (int q = 0; q < 4; ++q)
        creg[q] = c0[(size_t)(b0 + kq * 4 + q) * HID + j16];

    const int hoff = (b0 + jr) * HID + kq * 8;       // A-frag lane offset in slot
    const int qa   = (jr & 1) * 2;                   // this lane stores batches qa,qa+1
    const int stoff = (b0 + kq * 4 + qa) * HID + w * 16 + (jr & ~1);  // dword store elem

    s16x8 ha[16];
    // prologue: issue h loads (slot 0) + xp loads (t=0)
    {
        const unsigned short* hp = hbuf + hoff;
        #pragma unroll
        for (int kf = 0; kf < 16; ++kf) ha[kf] = llc_load16(hp + kf * 32);
    }
    uint2 xv0, xv1, xv2, xv3;
    {
        const unsigned short* xq = xp;
        xv0 = *(const uint2*)(xq + ((size_t)(0 * 512 + j16)) * 32 + b0 + kq * 4);
        xv1 = *(const uint2*)(xq + ((size_t)(1 * 512 + j16)) * 32 + b0 + kq * 4);
        xv2 = *(const uint2*)(xq + ((size_t)(2 * 512 + j16)) * 32 + b0 + kq * 4);
        xv3 = *(const uint2*)(xq + ((size_t)(3 * 512 + j16)) * 32 + b0 + kq * 4);
    }

    for (int t = 0; t < T_STEPS; ++t) {
        const int s0 = t % 3, s1 = (t + 1) % 3, s2 = (t + 2) % 3;

        // ---- wait + sentinel check (retry merges poll+load into one RT) ----
        while (true) {
            asm volatile("s_waitcnt vmcnt(0)" ::: "memory");
            __builtin_amdgcn_sched_barrier(0);
            u32 mx = 0;
            #pragma unroll
            for (int kf = 0; kf < 16; ++kf) {
                u32x4 d = __builtin_bit_cast(u32x4, ha[kf]);
                u32 a = d[0] > d[1] ? d[0] : d[1];
                u32 b = d[2] > d[3] ? d[2] : d[3];
                u32 c = a > b ? a : b;
                mx = mx > c ? mx : c;
            }
            if (!__any(mx == 0xFFFFFFFFu)) break;
            const unsigned short* hp = hbuf + s0 * SLOT_ELEMS + hoff;
            #pragma unroll
            for (int kf = 0; kf < 16; ++kf) ha[kf] = llc_load16(hp + kf * 32);
        }

        // ---- sentinel-restore slot s2 (our own cells; safe: slot s0 full =>
        //      everyone finished step t-1 => s2 (== s(t-1)) fully consumed) ----
        {
            unsigned short* rp = hbuf + s2 * SLOT_ELEMS + stoff;
            llc_store4(rp, 0xFFFFFFFFu);
            llc_store4(rp + HID, 0xFFFFFFFFu);
        }

        // ---- gates = xp + h @ Whh^T : 4 accumulator chains x 16 MFMA ----
        f32x4 acc[4];
        acc[0][0]=bf2f(xv0.x&0xFFFFu); acc[0][1]=bf2f(xv0.x>>16); acc[0][2]=bf2f(xv0.y&0xFFFFu); acc[0][3]=bf2f(xv0.y>>16);
        acc[1][0]=bf2f(xv1.x&0xFFFFu); acc[1][1]=bf2f(xv1.x>>16); acc[1][2]=bf2f(xv1.y&0xFFFFu); acc[1][3]=bf2f(xv1.y>>16);
        acc[2][0]=bf2f(xv2.x&0xFFFFu); acc[2][1]=bf2f(xv2.x>>16); acc[2][2]=bf2f(xv2.y&0xFFFFu); acc[2][3]=bf2f(xv2.y>>16);
        acc[3][0]=bf2f(xv3.x&0xFFFFu); acc[3][1]=bf2f(xv3.x>>16); acc[3][2]=bf2f(xv3.y&0xFFFFu); acc[3][3]=bf2f(xv3.y>>16);
        #pragma unroll
        for (int kf = 0; kf < 16; ++kf) {
            acc[0] = MFMA16(ha[kf], bw[0][kf], acc[0], 0, 0, 0);
            acc[1] = MFMA16(ha[kf], bw[1][kf], acc[1], 0, 0, 0);
            acc[2] = MFMA16(ha[kf], bw[2][kf], acc[2], 0, 0, 0);
            acc[3] = MFMA16(ha[kf], bw[3][kf], acc[3], 0, 0, 0);
        }

        // ---- cell update fully in-register ----
        float hv[4];
        #pragma unroll
        for (int q = 0; q < 4; ++q) {
            float ig = sigm(acc[0][q]);
            float fg = sigm(acc[1][q]);
            float gg = tanhfast(acc[2][q]);
            float og = sigm(acc[3][q]);
            creg[q] = fg * creg[q] + ig * gg;
            hv[q] = og * tanhfast(creg[q]);
        }

        // ---- drain sentinels (same-address order), then publish h (one-way) ----
        asm volatile("s_waitcnt vmcnt(0)" ::: "memory");
        {
            float p0 = __shfl_xor(hv[0], 1), p1 = __shfl_xor(hv[1], 1);
            float p2 = __shfl_xor(hv[2], 1), p3 = __shfl_xor(hv[3], 1);
            bool odd = (jr & 1);
            u32 pk0 = (u32)f2bf(odd ? p0 : hv[0]) | ((u32)f2bf(odd ? hv[0] : p0) << 16);
            u32 pk1 = (u32)f2bf(odd ? p1 : hv[1]) | ((u32)f2bf(odd ? hv[1] : p1) << 16);
            u32 pk2 = (u32)f2bf(odd ? p2 : hv[2]) | ((u32)f2bf(odd ? hv[2] : p2) << 16);
            u32 pk3 = (u32)f2bf(odd ? p3 : hv[3]) | ((u32)f2bf(odd ? hv[3] : p3) << 16);
            unsigned short* sp = hbuf + s1 * SLOT_ELEMS + stoff;
            llc_store4(sp,       odd ? pk2 : pk0);
            llc_store4(sp + HID, odd ? pk3 : pk1);
        }

        // ---- out stores (normal cached, off critical path) ----
        #pragma unroll
        for (int q = 0; q < 4; ++q)
            out[((size_t)t * BATCH + b0 + kq * 4 + q) * HID + j16] = hv[q];

        if (t == T_STEPS - 1) {
            #pragma unroll
            for (int q = 0; q < 4; ++q) {
                out[(size_t)T_STEPS * BATCH * HID + (size_t)(b0 + kq*4 + q) * HID + j16] = hv[q];
                out[(size_t)T_STEPS * BATCH * HID + BATCH * HID
                    + (size_t)(b0 + kq*4 + q) * HID + j16] = creg[q];
            }
        } else {
            // ---- prefetch xp for t+1 (normal cached) ----
            const unsigned short* xq = xp + (size_t)(t + 1) * NG * 32;
            xv0 = *(const uint2*)(xq + ((size_t)(0 * 512 + j16)) * 32 + b0 + kq * 4);
            xv1 = *(const uint2*)(xq + ((size_t)(1 * 512 + j16)) * 32 + b0 + kq * 4);
            xv2 = *(const uint2*)(xq + ((size_t)(2 * 512 + j16)) * 32 + b0 + kq * 4);
            xv3 = *(const uint2*)(xq + ((size_t)(3 * 512 + j16)) * 32 + b0 + kq * 4);
            // ---- issue next h loads (slot s1) ----
            const unsigned short* hp = hbuf + s1 * SLOT_ELEMS + hoff;
            #pragma unroll
            for (int kf = 0; kf < 16; ++kf) ha[kf] = llc_load16(hp + kf * 32);
        }
    }
}

extern "C" void kernel_launch(void* const* d_in, const int* in_sizes, int n_in,
                              void* d_out, int out_size, void* d_ws, size_t ws_size,
                              hipStream_t stream) {
    const float* x   = (const float*)d_in[0];
    const float* h0  = (const float*)d_in[1];
    const float* c0  = (const float*)d_in[2];
    const float* Wih = (const float*)d_in[3];
    const float* Whh = (const float*)d_in[4];
    const float* bih = (const float*)d_in[5];
    const float* bhh = (const float*)d_in[6];
    float* out = (float*)d_out;

    char* ws = (char*)d_ws;
    unsigned short* xp   = (unsigned short*)ws;                 // 256 MB
    unsigned short* hbuf = (unsigned short*)(ws + XP_BYTES);    // 96 KB

    init_k<<<dim3(192), dim3(256), 0, stream>>>(h0, hbuf);
    xproj_k<<<dim3(256), dim3(256), 0, stream>>>(x, Wih, bih, bhh, xp);
    rec_k<<<dim3(64), dim3(64), 0, stream>>>(xp, Whh, c0, hbuf, out);
}